// Round 3
// baseline (1345.665 us; speedup 1.0000x reference)
//
#include <hip/hip_runtime.h>
#include <math.h>

// EdgeConv, factorized:
//   A[i] = x[i] @ (W1_top - W1_bot) + b1        (64-dim f32, per node)
//   B[j] = x[j] @ W1_bot                        (64-dim f16, per node)
//   agg1[i] = sum_{e: dst=i} relu(A[i] + B[src_e])
//   out[i]  = tanh(agg1[i] @ W2 + deg_i * b2)
//
// Edge bucketing: slot[dst*64 + pos] = src via int atomicAdd on cnt[dst].
// Capacity 64: E=1.2M over N=100k -> Poisson(12), P(deg>64)~1e-30.

#define FDIM 64
typedef _Float16 f16;
typedef unsigned short u16;
typedef unsigned int u32;

__device__ __forceinline__ float h2f_lo(u32 u) {
    union { u16 s; f16 h; } c; c.s = (u16)(u & 0xffffu); return (float)c.h;
}
__device__ __forceinline__ float h2f_hi(u32 u) {
    union { u16 s; f16 h; } c; c.s = (u16)(u >> 16); return (float)c.h;
}
__device__ __forceinline__ u16 f2h(float f) {
    union { u16 s; f16 h; } c; c.h = (f16)f; return c.s;
}

// ---------------------------------------------------------------------------
// Kernel 1: per-node A (f32), B (f16) precompute.  64 nodes/block.
// ---------------------------------------------------------------------------
__global__ __launch_bounds__(256) void node_pre(
    const float* __restrict__ x, const float* __restrict__ W1,
    const float* __restrict__ b1, float* __restrict__ A,
    f16* __restrict__ Bmh, int N)
{
    __shared__ __align__(16) float Wc[64][132];   // [k][c]: c<64 A-weights, c>=64 B-weights
    __shared__ __align__(16) float xsT[64][72];   // [k][node]

    const int tid = threadIdx.x;
    const int node0 = blockIdx.x * 64;

    for (int i = tid; i < 64 * 128; i += 256) {
        int k = i >> 7, c = i & 127;
        int cc = c & 63;
        float wb = W1[(64 + k) * 64 + cc];
        Wc[k][c] = (c < 64) ? (W1[k * 64 + cc] - wb) : wb;
    }
    for (int i = tid; i < 64 * 64; i += 256) {
        int n = i >> 6, k = i & 63;
        int gn = node0 + n;
        xsT[k][n] = (gn < N) ? x[(size_t)gn * 64 + k] : 0.f;
    }
    __syncthreads();

    const int ng = tid & 15, cg = tid >> 4;   // 16 node-groups x 16 col-groups
    const int n0 = ng * 4, c0 = cg * 8;

    float acc[4][8];
    #pragma unroll
    for (int ci = 0; ci < 8; ++ci) {
        float init = (c0 + ci < 64) ? b1[c0 + ci] : 0.f;
        #pragma unroll
        for (int ni = 0; ni < 4; ++ni) acc[ni][ci] = init;
    }

    #pragma unroll 4
    for (int k = 0; k < 64; ++k) {
        float4 xv = *(const float4*)&xsT[k][n0];
        float4 wa = *(const float4*)&Wc[k][c0];
        float4 wb = *(const float4*)&Wc[k][c0 + 4];
        float xs[4] = {xv.x, xv.y, xv.z, xv.w};
        float ws[8] = {wa.x, wa.y, wa.z, wa.w, wb.x, wb.y, wb.z, wb.w};
        #pragma unroll
        for (int ni = 0; ni < 4; ++ni)
            #pragma unroll
            for (int ci = 0; ci < 8; ++ci)
                acc[ni][ci] += xs[ni] * ws[ci];
    }

    #pragma unroll
    for (int ni = 0; ni < 4; ++ni) {
        int n = node0 + n0 + ni;
        if (n >= N) break;
        if (c0 < 64) {
            float4 v0 = make_float4(acc[ni][0], acc[ni][1], acc[ni][2], acc[ni][3]);
            float4 v1 = make_float4(acc[ni][4], acc[ni][5], acc[ni][6], acc[ni][7]);
            ((float4*)A)[(size_t)n * 16 + (c0 >> 2)] = v0;
            ((float4*)A)[(size_t)n * 16 + (c0 >> 2) + 1] = v1;
        } else {
            u16 hs[8];
            #pragma unroll
            for (int t = 0; t < 8; ++t) hs[t] = f2h(acc[ni][t]);
            uint4 pk;
            pk.x = (u32)hs[0] | ((u32)hs[1] << 16);
            pk.y = (u32)hs[2] | ((u32)hs[3] << 16);
            pk.z = (u32)hs[4] | ((u32)hs[5] << 16);
            pk.w = (u32)hs[6] | ((u32)hs[7] << 16);
            *(uint4*)&Bmh[(size_t)n * 64 + (c0 - 64)] = pk;
        }
    }
}

// ---------------------------------------------------------------------------
// Kernel 2: bucket edges by dst.  4 edges/thread, atomics pipelined (MLP).
// ---------------------------------------------------------------------------
#define EPT 4
__global__ __launch_bounds__(256) void scatter_k(
    const int* __restrict__ ei, int* __restrict__ slot,
    int* __restrict__ cnt, int E)
{
    const int base = blockIdx.x * 256 + threadIdx.x;
    const int stride = gridDim.x * 256;
    int dv[EPT], sv[EPT], pv[EPT];
    #pragma unroll
    for (int i = 0; i < EPT; ++i) {
        int e = base + i * stride;
        dv[i] = (e < E) ? ei[E + e] : -1;
        sv[i] = (e < E) ? ei[e] : 0;
    }
    #pragma unroll
    for (int i = 0; i < EPT; ++i)
        pv[i] = (dv[i] >= 0) ? atomicAdd(&cnt[dv[i]], 1) : 64;
    #pragma unroll
    for (int i = 0; i < EPT; ++i)
        if (dv[i] >= 0 && pv[i] < 64) slot[(size_t)dv[i] * 64 + pv[i]] = sv[i];
}

// ---------------------------------------------------------------------------
// Kernel 3: fused aggregate + W2 GEMM + deg*b2 + tanh.  64 nodes/block.
// Phase 1: thread (g=tid>>3, q=tid&7) owns 8 features (16 B) of nodes
//   g, g+32; 4 independent f16x8 gathers in flight; acc f32; aggT f16.
// Phase 2: thread (ng=tid>>3, cg=tid&7) computes nodes {2ng,2ng+1} x cols
//   {8cg..8cg+7}; W2 in LDS f16 transposed [c][k] with XOR-swizzled
//   k-blocks (bank = 8ci + 4(kc^cg) mod 32 -> conflict-free).
// ---------------------------------------------------------------------------
__global__ __launch_bounds__(256, 4) void fused_agg(
    const float* __restrict__ A, const f16* __restrict__ Bmh,
    const int* __restrict__ slot, const int* __restrict__ cnt,
    const float* __restrict__ W2, const float* __restrict__ b2,
    float* __restrict__ out, int N)
{
    __shared__ __align__(16) u16 W2t[64][80];    // [c][k-swizzled], 10.2 KB
    __shared__ __align__(16) u16 aggTh[64][72];  // [node][k], 9.2 KB
    __shared__ int sls[64][68];                  // 17.4 KB (stride 68: no conflicts)
    __shared__ int degs[64];
    __shared__ float b2s[64];

    const int tid = threadIdx.x;
    const int node0 = blockIdx.x * 64;

    // Stage W2 -> transposed f16, swizzled: element (k,c) at [c][(kb^(c>>3))*8 + (k&7)]
    for (int i = tid; i < 1024; i += 256) {
        int k = i >> 4, c4 = (i & 15) * 4;
        float4 w = *(const float4*)&W2[k * 64 + c4];
        float ws4[4] = {w.x, w.y, w.z, w.w};
        int kb = k >> 3, ko = k & 7;
        #pragma unroll
        for (int t = 0; t < 4; ++t) {
            int c = c4 + t;
            W2t[c][((kb ^ (c >> 3)) << 3) + ko] = f2h(ws4[t]);
        }
    }
    if (tid < 64) {
        b2s[tid] = b2[tid];
        int gn = node0 + tid;
        degs[tid] = (gn < N) ? min(cnt[gn], 64) : 0;
    }
    for (int i = tid; i < 4096; i += 256) {
        int n = i >> 6, p = i & 63;
        int gn = node0 + n;
        int v = 0;
        if (gn < N && p < cnt[gn]) v = slot[(size_t)gn * 64 + p];
        sls[n][p] = v;
    }
    __syncthreads();

    // ---- Phase 1: gather-aggregate ----
    {
        const int q = tid & 7, g = tid >> 3;
        const float4* A4 = (const float4*)A;
        #pragma unroll
        for (int h = 0; h < 2; ++h) {
            int nl = h * 32 + g;
            int gn = node0 + nl;
            int d = (gn < N) ? degs[nl] : 0;
            float a[8];
            if (gn < N) {
                float4 a0 = A4[(size_t)gn * 16 + q * 2];
                float4 a1 = A4[(size_t)gn * 16 + q * 2 + 1];
                a[0] = a0.x; a[1] = a0.y; a[2] = a0.z; a[3] = a0.w;
                a[4] = a1.x; a[5] = a1.y; a[6] = a1.z; a[7] = a1.w;
            } else {
                #pragma unroll
                for (int t = 0; t < 8; ++t) a[t] = 0.f;
            }
            float acc[8] = {0.f, 0.f, 0.f, 0.f, 0.f, 0.f, 0.f, 0.f};
            for (int j0 = 0; j0 < d; j0 += 4) {
                int s0 = sls[nl][j0];
                int s1 = sls[nl][min(j0 + 1, d - 1)];
                int s2 = sls[nl][min(j0 + 2, d - 1)];
                int s3 = sls[nl][min(j0 + 3, d - 1)];
                uint4 b0 = *(const uint4*)&Bmh[(size_t)s0 * 64 + q * 8];
                uint4 b1 = *(const uint4*)&Bmh[(size_t)s1 * 64 + q * 8];
                uint4 b2v = *(const uint4*)&Bmh[(size_t)s2 * 64 + q * 8];
                uint4 b3v = *(const uint4*)&Bmh[(size_t)s3 * 64 + q * 8];
                bool m1 = j0 + 1 < d, m2 = j0 + 2 < d, m3 = j0 + 3 < d;
                uint4 bb[4] = {b0, b1, b2v, b3v};
                bool mm[4] = {true, m1, m2, m3};
                #pragma unroll
                for (int t = 0; t < 4; ++t) {
                    float bv[8] = {h2f_lo(bb[t].x), h2f_hi(bb[t].x),
                                   h2f_lo(bb[t].y), h2f_hi(bb[t].y),
                                   h2f_lo(bb[t].z), h2f_hi(bb[t].z),
                                   h2f_lo(bb[t].w), h2f_hi(bb[t].w)};
                    #pragma unroll
                    for (int u = 0; u < 8; ++u)
                        acc[u] += mm[t] ? fmaxf(a[u] + bv[u], 0.f) : 0.f;
                }
            }
            uint4 pk;
            pk.x = (u32)f2h(acc[0]) | ((u32)f2h(acc[1]) << 16);
            pk.y = (u32)f2h(acc[2]) | ((u32)f2h(acc[3]) << 16);
            pk.z = (u32)f2h(acc[4]) | ((u32)f2h(acc[5]) << 16);
            pk.w = (u32)f2h(acc[6]) | ((u32)f2h(acc[7]) << 16);
            *(uint4*)&aggTh[nl][q * 8] = pk;
        }
    }
    __syncthreads();

    // ---- Phase 2: [64x64] @ W2 + deg*b2, tanh ----
    {
        const int cg = tid & 7, ng = tid >> 3;
        const int c0 = cg * 8;
        const int n0l = 2 * ng, n1l = n0l + 1;
        const int gn0 = node0 + n0l, gn1 = node0 + n1l;
        float o0[8], o1[8];
        float dg0 = (float)degs[n0l], dg1 = (float)degs[n1l];
        #pragma unroll
        for (int ci = 0; ci < 8; ++ci) {
            float bv = b2s[c0 + ci];
            o0[ci] = dg0 * bv;
            o1[ci] = dg1 * bv;
        }
        #pragma unroll
        for (int kc = 0; kc < 8; ++kc) {
            uint4 ua0 = *(const uint4*)&aggTh[n0l][kc * 8];
            uint4 ua1 = *(const uint4*)&aggTh[n1l][kc * 8];
            float av0[8] = {h2f_lo(ua0.x), h2f_hi(ua0.x), h2f_lo(ua0.y), h2f_hi(ua0.y),
                            h2f_lo(ua0.z), h2f_hi(ua0.z), h2f_lo(ua0.w), h2f_hi(ua0.w)};
            float av1[8] = {h2f_lo(ua1.x), h2f_hi(ua1.x), h2f_lo(ua1.y), h2f_hi(ua1.y),
                            h2f_lo(ua1.z), h2f_hi(ua1.z), h2f_lo(ua1.w), h2f_hi(ua1.w)};
            const int kbs = (kc ^ cg) << 3;
            #pragma unroll
            for (int ci = 0; ci < 8; ++ci) {
                uint4 uw = *(const uint4*)&W2t[c0 + ci][kbs];
                float w[8] = {h2f_lo(uw.x), h2f_hi(uw.x), h2f_lo(uw.y), h2f_hi(uw.y),
                              h2f_lo(uw.z), h2f_hi(uw.z), h2f_lo(uw.w), h2f_hi(uw.w)};
                #pragma unroll
                for (int j = 0; j < 8; ++j) {
                    o0[ci] += av0[j] * w[j];
                    o1[ci] += av1[j] * w[j];
                }
            }
        }
        if (gn0 < N) {
            float4 r0 = make_float4(tanhf(o0[0]), tanhf(o0[1]), tanhf(o0[2]), tanhf(o0[3]));
            float4 r1 = make_float4(tanhf(o0[4]), tanhf(o0[5]), tanhf(o0[6]), tanhf(o0[7]));
            ((float4*)out)[(size_t)gn0 * 16 + cg * 2] = r0;
            ((float4*)out)[(size_t)gn0 * 16 + cg * 2 + 1] = r1;
        }
        if (gn1 < N) {
            float4 r0 = make_float4(tanhf(o1[0]), tanhf(o1[1]), tanhf(o1[2]), tanhf(o1[3]));
            float4 r1 = make_float4(tanhf(o1[4]), tanhf(o1[5]), tanhf(o1[6]), tanhf(o1[7]));
            ((float4*)out)[(size_t)gn1 * 16 + cg * 2] = r0;
            ((float4*)out)[(size_t)gn1 * 16 + cg * 2 + 1] = r1;
        }
    }
}

// ---------------------------------------------------------------------------
extern "C" void kernel_launch(void* const* d_in, const int* in_sizes, int n_in,
                              void* d_out, int out_size, void* d_ws, size_t ws_size,
                              hipStream_t stream)
{
    const float* x  = (const float*)d_in[0];
    const int*   ei = (const int*)d_in[1];     // [2,E]: row0=src, row1=dst
    const float* W1 = (const float*)d_in[2];   // [128,64]
    const float* b1 = (const float*)d_in[3];   // [64]
    const float* W2 = (const float*)d_in[4];   // [64,64]
    const float* b2 = (const float*)d_in[5];   // [64]
    float* out = (float*)d_out;

    const int N = in_sizes[0] / FDIM;          // 100000
    const int E = in_sizes[1] / 2;             // 1200000

    // Workspace (re-poisoned 0xAA every call; cnt zeroed below):
    float* A    = (float*)d_ws;                         // N*64 f32 = 25.6 MB
    f16*   Bmh  = (f16*)(A + (size_t)N * FDIM);         // N*64 f16 = 12.8 MB
    int*   slot = (int*)(Bmh + (size_t)N * FDIM);       // N*64 i32 = 25.6 MB
    int*   cnt  = slot + (size_t)N * FDIM;              // N   i32  =  0.4 MB

    hipMemsetAsync(cnt, 0, (size_t)N * sizeof(int), stream);

    node_pre<<<(N + 63) / 64, 256, 0, stream>>>(x, W1, b1, A, Bmh, N);
    scatter_k<<<(E + 256 * EPT - 1) / (256 * EPT), 256, 0, stream>>>(ei, slot, cnt, E);
    fused_agg<<<(N + 63) / 64, 256, 0, stream>>>(A, Bmh, slot, cnt, W2, b2, out, N);
}

// Round 4
// 290.459 us; speedup vs baseline: 4.6329x; 4.6329x over previous
//
#include <hip/hip_runtime.h>
#include <math.h>

// EdgeConv, factorized:
//   A[i] = x[i] @ (W1_top - W1_bot) + b1        (64-dim f32, per node)
//   B[j] = x[j] @ W1_bot                        (64-dim bf16, per node)
//   agg1[i] = sum_{e: dst=i} relu(A[i] + B[src_e])
//   out[i]  = tanh(agg1[i] @ W2 + deg_i * b2)
//
// Edge bucketing: slot[dst*64 + pos] = src via int atomicAdd on cnt[dst].
// Capacity 64: E=1.2M over N=100k -> Poisson(12), P(deg>64)~1e-30.
//
// R3 lesson: keep register footprint small (R2's fused_agg = 52 VGPR, no
// spills). This is R2's exact structure; ONLY the gather payload is bf16.

#define FDIM 64
typedef unsigned int u32;
typedef unsigned short u16;

__device__ __forceinline__ float bf_lo(u32 u) {
    union { u32 i; float f; } c; c.i = u << 16; return c.f;
}
__device__ __forceinline__ float bf_hi(u32 u) {
    union { u32 i; float f; } c; c.i = u & 0xffff0000u; return c.f;
}
__device__ __forceinline__ u32 f2bf_rne(float f) {
    union { float f; u32 u; } c; c.f = f;
    u32 u = c.u;
    u += 0x7fffu + ((u >> 16) & 1u);   // round-to-nearest-even
    return u >> 16;
}

// ---------------------------------------------------------------------------
// Kernel 1: per-node A (f32), B (bf16) precompute.  64 nodes/block.
// ---------------------------------------------------------------------------
__global__ __launch_bounds__(256) void node_pre(
    const float* __restrict__ x, const float* __restrict__ W1,
    const float* __restrict__ b1, float* __restrict__ A,
    u16* __restrict__ Bmh, int N)
{
    __shared__ __align__(16) float Wc[64][132];   // [k][c]: c<64 A-wt, c>=64 B-wt
    __shared__ __align__(16) float xsT[64][72];   // [k][node]

    const int tid = threadIdx.x;
    const int node0 = blockIdx.x * 64;

    for (int i = tid; i < 64 * 128; i += 256) {
        int k = i >> 7, c = i & 127;
        int cc = c & 63;
        float wb = W1[(64 + k) * 64 + cc];
        Wc[k][c] = (c < 64) ? (W1[k * 64 + cc] - wb) : wb;
    }
    for (int i = tid; i < 64 * 64; i += 256) {
        int n = i >> 6, k = i & 63;
        int gn = node0 + n;
        xsT[k][n] = (gn < N) ? x[(size_t)gn * 64 + k] : 0.f;
    }
    __syncthreads();

    const int ng = tid & 15, cg = tid >> 4;   // 16 node-groups x 16 col-groups
    const int n0 = ng * 4, c0 = cg * 8;

    float acc[4][8];
    #pragma unroll
    for (int ci = 0; ci < 8; ++ci) {
        float init = (c0 + ci < 64) ? b1[c0 + ci] : 0.f;
        #pragma unroll
        for (int ni = 0; ni < 4; ++ni) acc[ni][ci] = init;
    }

    #pragma unroll 4
    for (int k = 0; k < 64; ++k) {
        float4 xv = *(const float4*)&xsT[k][n0];
        float4 wa = *(const float4*)&Wc[k][c0];
        float4 wb = *(const float4*)&Wc[k][c0 + 4];
        float xs[4] = {xv.x, xv.y, xv.z, xv.w};
        float ws[8] = {wa.x, wa.y, wa.z, wa.w, wb.x, wb.y, wb.z, wb.w};
        #pragma unroll
        for (int ni = 0; ni < 4; ++ni)
            #pragma unroll
            for (int ci = 0; ci < 8; ++ci)
                acc[ni][ci] += xs[ni] * ws[ci];
    }

    #pragma unroll
    for (int ni = 0; ni < 4; ++ni) {
        int n = node0 + n0 + ni;
        if (n >= N) break;
        if (c0 < 64) {
            float4 v0 = make_float4(acc[ni][0], acc[ni][1], acc[ni][2], acc[ni][3]);
            float4 v1 = make_float4(acc[ni][4], acc[ni][5], acc[ni][6], acc[ni][7]);
            ((float4*)A)[(size_t)n * 16 + (c0 >> 2)] = v0;
            ((float4*)A)[(size_t)n * 16 + (c0 >> 2) + 1] = v1;
        } else {
            uint4 pk;
            pk.x = f2bf_rne(acc[ni][0]) | (f2bf_rne(acc[ni][1]) << 16);
            pk.y = f2bf_rne(acc[ni][2]) | (f2bf_rne(acc[ni][3]) << 16);
            pk.z = f2bf_rne(acc[ni][4]) | (f2bf_rne(acc[ni][5]) << 16);
            pk.w = f2bf_rne(acc[ni][6]) | (f2bf_rne(acc[ni][7]) << 16);
            *(uint4*)&Bmh[(size_t)n * 64 + (c0 - 64)] = pk;
        }
    }
}

// ---------------------------------------------------------------------------
// Kernel 2: bucket edges by dst.  4 edges/thread, atomics pipelined (MLP).
// ---------------------------------------------------------------------------
#define EPT 4
__global__ __launch_bounds__(256) void scatter_k(
    const int* __restrict__ ei, int* __restrict__ slot,
    int* __restrict__ cnt, int E)
{
    const int base = blockIdx.x * 256 + threadIdx.x;
    const int stride = gridDim.x * 256;
    int dv[EPT], sv[EPT], pv[EPT];
    #pragma unroll
    for (int i = 0; i < EPT; ++i) {
        int e = base + i * stride;
        dv[i] = (e < E) ? ei[E + e] : -1;
        sv[i] = (e < E) ? ei[e] : 0;
    }
    #pragma unroll
    for (int i = 0; i < EPT; ++i)
        pv[i] = (dv[i] >= 0) ? atomicAdd(&cnt[dv[i]], 1) : 64;
    #pragma unroll
    for (int i = 0; i < EPT; ++i)
        if (dv[i] >= 0 && pv[i] < 64) slot[(size_t)dv[i] * 64 + pv[i]] = sv[i];
}

// ---------------------------------------------------------------------------
// Kernel 3: fused aggregate + W2 GEMM + deg*b2 + tanh.  32 nodes/block.
// (R2 structure verbatim; gather payload bf16 instead of f32.)
// Phase 1: thread (n = tid>>4, q = tid&15) owns feature-quad q of node n
// (+16): edge loop x4 -> 4 independent coalesced 8B gathers in flight.
// Phase 2: [32x64] @ W2 from LDS, tanh, store.
// ---------------------------------------------------------------------------
__device__ __forceinline__ float4 relu4add(float4 acc, float4 a, float4 b) {
    acc.x += fmaxf(a.x + b.x, 0.f);
    acc.y += fmaxf(a.y + b.y, 0.f);
    acc.z += fmaxf(a.z + b.z, 0.f);
    acc.w += fmaxf(a.w + b.w, 0.f);
    return acc;
}
__device__ __forceinline__ float4 relu4add_m(float4 acc, float4 a, float4 b, bool m) {
    acc.x += m ? fmaxf(a.x + b.x, 0.f) : 0.f;
    acc.y += m ? fmaxf(a.y + b.y, 0.f) : 0.f;
    acc.z += m ? fmaxf(a.z + b.z, 0.f) : 0.f;
    acc.w += m ? fmaxf(a.w + b.w, 0.f) : 0.f;
    return acc;
}
__device__ __forceinline__ float4 bf4(uint2 u) {
    return make_float4(bf_lo(u.x), bf_hi(u.x), bf_lo(u.y), bf_hi(u.y));
}

__global__ __launch_bounds__(256) void fused_agg(
    const float* __restrict__ A, const u16* __restrict__ Bmh,
    const int* __restrict__ slot, const int* __restrict__ cnt,
    const float* __restrict__ W2, const float* __restrict__ b2,
    float* __restrict__ out, int N)
{
    __shared__ __align__(16) float W2s[64][68];
    __shared__ __align__(16) float aggT[32][68];
    __shared__ int sls[32][64];
    __shared__ int degs[32];

    const int tid = threadIdx.x;
    const int node0 = blockIdx.x * 32;
    const uint2* __restrict__ B2 = (const uint2*)Bmh;   // 8B = 4 bf16

    for (int i = tid; i < 4096; i += 256) W2s[i >> 6][i & 63] = W2[i];
    for (int i = tid; i < 2048; i += 256) {
        int n = i >> 6, p = i & 63;
        int gn = node0 + n;
        int v = 0;
        if (gn < N) {
            int c = cnt[gn];
            if (p < c) v = slot[(size_t)gn * 64 + p];
        }
        sls[n][p] = v;
    }
    if (tid < 32) {
        int gn = node0 + tid;
        degs[tid] = (gn < N) ? min(cnt[gn], 64) : 0;
    }
    __syncthreads();

    const int q = tid & 15;          // feature quad
    const int nbase = tid >> 4;      // node 0..15; also handles +16
    #pragma unroll
    for (int h = 0; h < 2; ++h) {
        int nl = nbase + h * 16;
        int gn = node0 + nl;
        int d = degs[nl];
        float4 a = make_float4(0.f, 0.f, 0.f, 0.f);
        if (gn < N) a = ((const float4*)A)[(size_t)gn * 16 + q];
        float4 acc = make_float4(0.f, 0.f, 0.f, 0.f);

        const int dfull = d & ~3;
        int j = 0;
        for (; j < dfull; j += 4) {
            int s0 = sls[nl][j + 0];
            int s1 = sls[nl][j + 1];
            int s2 = sls[nl][j + 2];
            int s3 = sls[nl][j + 3];
            uint2 b0 = B2[(size_t)s0 * 16 + q];
            uint2 b1v = B2[(size_t)s1 * 16 + q];
            uint2 b2v = B2[(size_t)s2 * 16 + q];
            uint2 b3v = B2[(size_t)s3 * 16 + q];
            acc = relu4add(acc, a, bf4(b0));
            acc = relu4add(acc, a, bf4(b1v));
            acc = relu4add(acc, a, bf4(b2v));
            acc = relu4add(acc, a, bf4(b3v));
        }
        if (j < d) {                 // tail: 1..3 edges, clamped + predicated
            int s0 = sls[nl][j];
            int s1 = sls[nl][min(j + 1, d - 1)];
            int s2 = sls[nl][min(j + 2, d - 1)];
            uint2 b0 = B2[(size_t)s0 * 16 + q];
            uint2 b1v = B2[(size_t)s1 * 16 + q];
            uint2 b2v = B2[(size_t)s2 * 16 + q];
            acc = relu4add(acc, a, bf4(b0));
            acc = relu4add_m(acc, a, bf4(b1v), j + 1 < d);
            acc = relu4add_m(acc, a, bf4(b2v), j + 2 < d);
        }
        *(float4*)&aggT[nl][q * 4] = acc;
    }
    __syncthreads();

    const int cg = tid & 15, ng = tid >> 4;   // 16 col-groups x 16 nodes (+16)
    const int c0 = cg * 4;
    #pragma unroll
    for (int h = 0; h < 2; ++h) {
        int nl = ng + h * 16;
        int n = node0 + nl;
        if (n >= N) continue;
        float dg = (float)degs[nl];
        float o0 = dg * b2[c0 + 0];
        float o1 = dg * b2[c0 + 1];
        float o2 = dg * b2[c0 + 2];
        float o3 = dg * b2[c0 + 3];
        #pragma unroll 8
        for (int k = 0; k < 64; ++k) {
            float av = aggT[nl][k];
            float4 wv = *(const float4*)&W2s[k][c0];
            o0 += av * wv.x; o1 += av * wv.y; o2 += av * wv.z; o3 += av * wv.w;
        }
        float4 r = make_float4(tanhf(o0), tanhf(o1), tanhf(o2), tanhf(o3));
        ((float4*)out)[(size_t)n * 16 + cg] = r;
    }
}

// ---------------------------------------------------------------------------
extern "C" void kernel_launch(void* const* d_in, const int* in_sizes, int n_in,
                              void* d_out, int out_size, void* d_ws, size_t ws_size,
                              hipStream_t stream)
{
    const float* x  = (const float*)d_in[0];
    const int*   ei = (const int*)d_in[1];     // [2,E]: row0=src, row1=dst
    const float* W1 = (const float*)d_in[2];   // [128,64]
    const float* b1 = (const float*)d_in[3];   // [64]
    const float* W2 = (const float*)d_in[4];   // [64,64]
    const float* b2 = (const float*)d_in[5];   // [64]
    float* out = (float*)d_out;

    const int N = in_sizes[0] / FDIM;          // 100000
    const int E = in_sizes[1] / 2;             // 1200000

    // Workspace (re-poisoned 0xAA every call; cnt zeroed below):
    float* A    = (float*)d_ws;                         // N*64 f32  = 25.6 MB
    u16*   Bmh  = (u16*)(A + (size_t)N * FDIM);         // N*64 bf16 = 12.8 MB
    int*   slot = (int*)(Bmh + (size_t)N * FDIM);       // N*64 i32  = 25.6 MB
    int*   cnt  = slot + (size_t)N * FDIM;              // N   i32   =  0.4 MB

    hipMemsetAsync(cnt, 0, (size_t)N * sizeof(int), stream);

    node_pre<<<(N + 63) / 64, 256, 0, stream>>>(x, W1, b1, A, Bmh, N);
    scatter_k<<<(E + 256 * EPT - 1) / (256 * EPT), 256, 0, stream>>>(ei, slot, cnt, E);
    fused_agg<<<(N + 31) / 32, 256, 0, stream>>>(A, Bmh, slot, cnt, W2, b2, out, N);
}

// Round 6
// 232.595 us; speedup vs baseline: 5.7854x; 1.2488x over previous
//
#include <hip/hip_runtime.h>
#include <math.h>

// EdgeConv, factorized:
//   A[i] = x[i] @ (W1_top - W1_bot) + b1        (64-dim f32, per node)
//   B[j] = x[j] @ W1_bot                        (64-dim bf16, per node)
//   agg1[i] = sum_{e: dst=i} relu(A[i] + B[src_e])
//   out[i]  = tanh(agg1[i] @ W2 + deg_i * b2)
//
// Edge shuffle: two-level binning into 128-node buckets (bin_k), then
// per-bucket LDS counting-sort to CSR inside fused_agg.
// R5 lesson: aggT staged in bf16 cost 0.04 absmax (|agg|~16 -> ulp 0.06);
// f16 staging (2^-12 rel) brings it back under budget. B-gather stays bf16
// (R4-proven at 0.0059).

#define FDIM 64
#define BN 128            // nodes per bucket
#define BSH 7             // log2(BN)
#define CAPB 2048         // bucket capacity (mean 1536, +13 sigma)
#define MAXB 1024         // LDS bucket-counter array bound in bin_k
#define EPB 4096          // edges per bin_k block

typedef unsigned int u32;
typedef unsigned short u16;
typedef _Float16 hf;

__device__ __forceinline__ float bf_lo(u32 u) {
    union { u32 i; float f; } c; c.i = u << 16; return c.f;
}
__device__ __forceinline__ float bf_hi(u32 u) {
    union { u32 i; float f; } c; c.i = u & 0xffff0000u; return c.f;
}
__device__ __forceinline__ u32 f2bf_rne(float f) {
    union { float f; u32 u; } c; c.f = f;
    u32 u = c.u;
    u += 0x7fffu + ((u >> 16) & 1u);   // round-to-nearest-even
    return u >> 16;
}
__device__ __forceinline__ u32 f2h(float f) {
    union { u16 s; hf h; } c; c.h = (hf)f; return (u32)c.s;
}
__device__ __forceinline__ float h_lo(u32 u) {
    union { u16 s; hf h; } c; c.s = (u16)(u & 0xffffu); return (float)c.h;
}
__device__ __forceinline__ float h_hi(u32 u) {
    union { u16 s; hf h; } c; c.s = (u16)(u >> 16); return (float)c.h;
}

// ---------------------------------------------------------------------------
// Kernel 1: per-node A (f32), B (bf16) precompute.  64 nodes/block.
// ---------------------------------------------------------------------------
__global__ __launch_bounds__(256) void node_pre(
    const float* __restrict__ x, const float* __restrict__ W1,
    const float* __restrict__ b1, float* __restrict__ A,
    u16* __restrict__ Bmh, int N)
{
    __shared__ __align__(16) float Wc[64][132];   // [k][c]: c<64 A-wt, c>=64 B-wt
    __shared__ __align__(16) float xsT[64][72];   // [k][node]

    const int tid = threadIdx.x;
    const int node0 = blockIdx.x * 64;

    for (int i = tid; i < 64 * 128; i += 256) {
        int k = i >> 7, c = i & 127;
        int cc = c & 63;
        float wb = W1[(64 + k) * 64 + cc];
        Wc[k][c] = (c < 64) ? (W1[k * 64 + cc] - wb) : wb;
    }
    for (int i = tid; i < 64 * 64; i += 256) {
        int n = i >> 6, k = i & 63;
        int gn = node0 + n;
        xsT[k][n] = (gn < N) ? x[(size_t)gn * 64 + k] : 0.f;
    }
    __syncthreads();

    const int ng = tid & 15, cg = tid >> 4;
    const int n0 = ng * 4, c0 = cg * 8;

    float acc[4][8];
    #pragma unroll
    for (int ci = 0; ci < 8; ++ci) {
        float init = (c0 + ci < 64) ? b1[c0 + ci] : 0.f;
        #pragma unroll
        for (int ni = 0; ni < 4; ++ni) acc[ni][ci] = init;
    }

    #pragma unroll 4
    for (int k = 0; k < 64; ++k) {
        float4 xv = *(const float4*)&xsT[k][n0];
        float4 wa = *(const float4*)&Wc[k][c0];
        float4 wb = *(const float4*)&Wc[k][c0 + 4];
        float xs[4] = {xv.x, xv.y, xv.z, xv.w};
        float ws[8] = {wa.x, wa.y, wa.z, wa.w, wb.x, wb.y, wb.z, wb.w};
        #pragma unroll
        for (int ni = 0; ni < 4; ++ni)
            #pragma unroll
            for (int ci = 0; ci < 8; ++ci)
                acc[ni][ci] += xs[ni] * ws[ci];
    }

    #pragma unroll
    for (int ni = 0; ni < 4; ++ni) {
        int n = node0 + n0 + ni;
        if (n >= N) break;
        if (c0 < 64) {
            float4 v0 = make_float4(acc[ni][0], acc[ni][1], acc[ni][2], acc[ni][3]);
            float4 v1 = make_float4(acc[ni][4], acc[ni][5], acc[ni][6], acc[ni][7]);
            ((float4*)A)[(size_t)n * 16 + (c0 >> 2)] = v0;
            ((float4*)A)[(size_t)n * 16 + (c0 >> 2) + 1] = v1;
        } else {
            uint4 pk;
            pk.x = f2bf_rne(acc[ni][0]) | (f2bf_rne(acc[ni][1]) << 16);
            pk.y = f2bf_rne(acc[ni][2]) | (f2bf_rne(acc[ni][3]) << 16);
            pk.z = f2bf_rne(acc[ni][4]) | (f2bf_rne(acc[ni][5]) << 16);
            pk.w = f2bf_rne(acc[ni][6]) | (f2bf_rne(acc[ni][7]) << 16);
            *(uint4*)&Bmh[(size_t)n * 64 + (c0 - 64)] = pk;
        }
    }
}

// ---------------------------------------------------------------------------
// Kernel 2: two-level binning (unchanged from R5).
// ---------------------------------------------------------------------------
__global__ __launch_bounds__(256) void bin_k(
    const int* __restrict__ ei, u32* __restrict__ slotB,
    int* __restrict__ gcnt, int E, int NB)
{
    __shared__ int histL[MAXB];
    __shared__ int gbase[MAXB];

    const int tid = threadIdx.x;
    const int e0 = blockIdx.x * EPB;

    for (int j = tid; j < NB; j += 256) histL[j] = 0;
    __syncthreads();

    #pragma unroll
    for (int i = 0; i < EPB / 256; ++i) {
        int e = e0 + i * 256 + tid;
        if (e < E) {
            int d = ei[E + e];
            atomicAdd(&histL[d >> BSH], 1);
        }
    }
    __syncthreads();

    for (int j = tid; j < NB; j += 256) {
        int h = histL[j];
        gbase[j] = (h > 0) ? atomicAdd(&gcnt[j], h) : 0;
        histL[j] = 0;                     // reuse as local append pos
    }
    __syncthreads();

    #pragma unroll
    for (int i = 0; i < EPB / 256; ++i) {
        int e = e0 + i * 256 + tid;
        if (e < E) {
            int s = ei[e];
            int d = ei[E + e];
            int b = d >> BSH;
            int pos = gbase[b] + atomicAdd(&histL[b], 1);
            if (pos < CAPB)
                slotB[(size_t)b * CAPB + pos] = ((u32)(d & (BN - 1)) << 20) | (u32)s;
        }
    }
}

// ---------------------------------------------------------------------------
// Kernel 3: per-bucket CSR build + aggregate + W2 GEMM + tanh.
// (R5 structure; aggT staged f16 instead of bf16.)
// ---------------------------------------------------------------------------
__device__ __forceinline__ float4 relu4add(float4 acc, float4 a, float4 b) {
    acc.x += fmaxf(a.x + b.x, 0.f);
    acc.y += fmaxf(a.y + b.y, 0.f);
    acc.z += fmaxf(a.z + b.z, 0.f);
    acc.w += fmaxf(a.w + b.w, 0.f);
    return acc;
}
__device__ __forceinline__ float4 relu4add_m(float4 acc, float4 a, float4 b, bool m) {
    acc.x += m ? fmaxf(a.x + b.x, 0.f) : 0.f;
    acc.y += m ? fmaxf(a.y + b.y, 0.f) : 0.f;
    acc.z += m ? fmaxf(a.z + b.z, 0.f) : 0.f;
    acc.w += m ? fmaxf(a.w + b.w, 0.f) : 0.f;
    return acc;
}
__device__ __forceinline__ float4 bf4(uint2 u) {
    return make_float4(bf_lo(u.x), bf_hi(u.x), bf_lo(u.y), bf_hi(u.y));
}

__global__ __launch_bounds__(256) void fused_agg(
    const float* __restrict__ A, const u16* __restrict__ Bmh,
    const u32* __restrict__ slotB, const int* __restrict__ gcnt,
    const float* __restrict__ W2, const float* __restrict__ b2,
    float* __restrict__ out, int N)
{
    __shared__ __align__(16) float W2s[64][68];      // 17.4 KB
    __shared__ __align__(16) u32 pool[BN * 17 * 2];  // 17.4 KB: eStage then aggTb
    __shared__ u32 csrS[CAPB];                       // 8 KB
    __shared__ int histL[BN];
    __shared__ int rowO[BN + 1];
    __shared__ int ofs[BN];
    __shared__ float b2s[64];

    u32* eStage = pool;                              // [CAPB] (phase: CSR build)
    uint2* aggTb = (uint2*)pool;                     // [BN][17] (phase: agg)

    const int tid = threadIdx.x;
    const int b = blockIdx.x;
    const int node0 = b * BN;
    const int cntB = min(gcnt[b], CAPB);

    for (int i = tid; i < 1024; i += 256)
        *(float4*)&W2s[i >> 4][(i & 15) * 4] = ((const float4*)W2)[i];
    if (tid < 64) b2s[tid] = b2[tid];
    if (tid < BN) histL[tid] = 0;
    __syncthreads();

    for (int i = tid; i < cntB; i += 256) {
        u32 e = slotB[(size_t)b * CAPB + i];
        eStage[i] = e;
        atomicAdd(&histL[e >> 20], 1);
    }
    __syncthreads();

    if (tid < 64) {                                  // exclusive scan of 128 bins
        int l = tid;
        int h0 = histL[2 * l], h1 = histL[2 * l + 1];
        int s = h0 + h1, inc = s;
        #pragma unroll
        for (int off = 1; off < 64; off <<= 1) {
            int t = __shfl_up(inc, off);
            if (l >= off) inc += t;
        }
        int base = inc - s;
        rowO[2 * l] = base; rowO[2 * l + 1] = base + h0;
        ofs[2 * l] = base;  ofs[2 * l + 1] = base + h0;
        if (l == 63) rowO[BN] = inc;
    }
    __syncthreads();

    for (int i = tid; i < cntB; i += 256) {
        u32 e = eStage[i];
        int pos = atomicAdd(&ofs[e >> 20], 1);
        csrS[pos] = e & 0xFFFFFu;
    }
    __syncthreads();                                 // eStage dead; aggTb live

    // ---- Phase 1: gather-aggregate (aggT packed f16) ----
    {
        const int q = tid & 15, ng = tid >> 4;
        const uint2* __restrict__ B2 = (const uint2*)Bmh;
        #pragma unroll
        for (int h = 0; h < 8; ++h) {
            int nl = ng + h * 16;
            int gn = node0 + nl;
            int start = rowO[nl];
            int d = (gn < N) ? (rowO[nl + 1] - start) : 0;
            float4 a = make_float4(0.f, 0.f, 0.f, 0.f);
            if (gn < N) a = ((const float4*)A)[(size_t)gn * 16 + q];
            float4 acc = make_float4(0.f, 0.f, 0.f, 0.f);

            const int dfull = d & ~3;
            int j = 0;
            for (; j < dfull; j += 4) {
                int s0 = csrS[start + j + 0];
                int s1 = csrS[start + j + 1];
                int s2 = csrS[start + j + 2];
                int s3 = csrS[start + j + 3];
                uint2 b0 = B2[(size_t)s0 * 16 + q];
                uint2 b1v = B2[(size_t)s1 * 16 + q];
                uint2 b2v = B2[(size_t)s2 * 16 + q];
                uint2 b3v = B2[(size_t)s3 * 16 + q];
                acc = relu4add(acc, a, bf4(b0));
                acc = relu4add(acc, a, bf4(b1v));
                acc = relu4add(acc, a, bf4(b2v));
                acc = relu4add(acc, a, bf4(b3v));
            }
            if (j < d) {
                int s0 = csrS[start + j];
                int s1 = csrS[start + min(j + 1, d - 1)];
                int s2 = csrS[start + min(j + 2, d - 1)];
                uint2 b0 = B2[(size_t)s0 * 16 + q];
                uint2 b1v = B2[(size_t)s1 * 16 + q];
                uint2 b2v = B2[(size_t)s2 * 16 + q];
                acc = relu4add(acc, a, bf4(b0));
                acc = relu4add_m(acc, a, bf4(b1v), j + 1 < d);
                acc = relu4add_m(acc, a, bf4(b2v), j + 2 < d);
            }
            uint2 pk;
            pk.x = f2h(acc.x) | (f2h(acc.y) << 16);
            pk.y = f2h(acc.z) | (f2h(acc.w) << 16);
            aggTb[nl * 17 + q] = pk;
        }
    }
    __syncthreads();

    // ---- Phase 2: [128x64] @ W2 + deg*b2, tanh; W2 shared across 4 nodes ----
    {
        const int cg = tid & 15, g0 = tid >> 4;
        const int c0 = cg * 4;
        #pragma unroll
        for (int h = 0; h < 2; ++h) {
            int g = g0 + h * 16;       // 0..31
            int nb0 = g * 4;           // nodes nb0..nb0+3 (adjacent: bank-safe)
            float o[4][4];
            #pragma unroll
            for (int ni = 0; ni < 4; ++ni) {
                float dg = (float)(rowO[nb0 + ni + 1] - rowO[nb0 + ni]);
                #pragma unroll
                for (int ci = 0; ci < 4; ++ci) o[ni][ci] = dg * b2s[c0 + ci];
            }
            #pragma unroll 2
            for (int kc = 0; kc < 16; ++kc) {
                uint2 u0 = aggTb[(nb0 + 0) * 17 + kc];
                uint2 u1 = aggTb[(nb0 + 1) * 17 + kc];
                uint2 u2 = aggTb[(nb0 + 2) * 17 + kc];
                uint2 u3 = aggTb[(nb0 + 3) * 17 + kc];
                #pragma unroll
                for (int kk = 0; kk < 4; ++kk) {
                    float4 wv = *(const float4*)&W2s[kc * 4 + kk][c0];
                    float a0 = (kk < 2) ? ((kk == 0) ? h_lo(u0.x) : h_hi(u0.x))
                                        : ((kk == 2) ? h_lo(u0.y) : h_hi(u0.y));
                    float a1 = (kk < 2) ? ((kk == 0) ? h_lo(u1.x) : h_hi(u1.x))
                                        : ((kk == 2) ? h_lo(u1.y) : h_hi(u1.y));
                    float a2 = (kk < 2) ? ((kk == 0) ? h_lo(u2.x) : h_hi(u2.x))
                                        : ((kk == 2) ? h_lo(u2.y) : h_hi(u2.y));
                    float a3 = (kk < 2) ? ((kk == 0) ? h_lo(u3.x) : h_hi(u3.x))
                                        : ((kk == 2) ? h_lo(u3.y) : h_hi(u3.y));
                    o[0][0] += a0 * wv.x; o[0][1] += a0 * wv.y; o[0][2] += a0 * wv.z; o[0][3] += a0 * wv.w;
                    o[1][0] += a1 * wv.x; o[1][1] += a1 * wv.y; o[1][2] += a1 * wv.z; o[1][3] += a1 * wv.w;
                    o[2][0] += a2 * wv.x; o[2][1] += a2 * wv.y; o[2][2] += a2 * wv.z; o[2][3] += a2 * wv.w;
                    o[3][0] += a3 * wv.x; o[3][1] += a3 * wv.y; o[3][2] += a3 * wv.z; o[3][3] += a3 * wv.w;
                }
            }
            #pragma unroll
            for (int ni = 0; ni < 4; ++ni) {
                int gn = node0 + nb0 + ni;
                if (gn < N) {
                    float4 r = make_float4(tanhf(o[ni][0]), tanhf(o[ni][1]),
                                           tanhf(o[ni][2]), tanhf(o[ni][3]));
                    ((float4*)out)[(size_t)gn * 16 + cg] = r;
                }
            }
        }
    }
}

// ---------------------------------------------------------------------------
extern "C" void kernel_launch(void* const* d_in, const int* in_sizes, int n_in,
                              void* d_out, int out_size, void* d_ws, size_t ws_size,
                              hipStream_t stream)
{
    const float* x  = (const float*)d_in[0];
    const int*   ei = (const int*)d_in[1];     // [2,E]: row0=src, row1=dst
    const float* W1 = (const float*)d_in[2];   // [128,64]
    const float* b1 = (const float*)d_in[3];   // [64]
    const float* W2 = (const float*)d_in[4];   // [64,64]
    const float* b2 = (const float*)d_in[5];   // [64]
    float* out = (float*)d_out;

    const int N = in_sizes[0] / FDIM;          // 100000
    const int E = in_sizes[1] / 2;             // 1200000
    const int NB = (N + BN - 1) / BN;          // 782 buckets

    // Workspace (re-poisoned 0xAA every call; gcnt zeroed below):
    float* A     = (float*)d_ws;                        // N*64 f32  = 25.6 MB
    u16*   Bmh   = (u16*)(A + (size_t)N * FDIM);        // N*64 bf16 = 12.8 MB
    u32*   slotB = (u32*)(Bmh + (size_t)N * FDIM);      // NB*CAPB u32 = 6.4 MB
    int*   gcnt  = (int*)(slotB + (size_t)NB * CAPB);   // NB i32

    hipMemsetAsync(gcnt, 0, (size_t)NB * sizeof(int), stream);

    node_pre<<<(N + 63) / 64, 256, 0, stream>>>(x, W1, b1, A, Bmh, N);
    bin_k<<<(E + EPB - 1) / EPB, 256, 0, stream>>>(ei, slotB, gcnt, E, NB);
    fused_agg<<<NB, 256, 0, stream>>>(A, Bmh, slotB, gcnt, W2, b2, out, N);
}

// Round 7
// 214.182 us; speedup vs baseline: 6.2828x; 1.0860x over previous
//
#include <hip/hip_runtime.h>
#include <math.h>

// EdgeConv, factorized:
//   A[i] = x[i] @ (W1_top - W1_bot) + b1        (64-dim f16, per node)
//   B[j] = x[j] @ W1_bot                        (64-dim bf16, per node)
//   agg1[i] = sum_{e: dst=i} relu(A[i] + B[src_e])
//   out[i]  = tanh(agg1[i] @ W2 + deg_i * b2)
//
// R6 -> R7: node_pre and bin_k are independent; merged into ONE dispatch
// (prep_k) with interleaved block types (5 pre : 1 bin) so the two
// latency-bound phases overlap instead of serializing (~149 us -> ~max).
// A stored f16 (halves its write+fetch). Transpose-staging writes remapped
// to be bank-conflict-free (lanes span nodes: bank = n%32, 2-way = free).

#define FDIM 64
#define BN 128            // nodes per bucket
#define BSH 7             // log2(BN)
#define CAPB 2048         // bucket capacity (mean 1536, +13 sigma)
#define MAXB 1024         // LDS bucket-counter array bound in bin branch
#define EPB 4096          // edges per bin block
#define PRE_SMEM 52224    // bytes: Wc 33792 + xsT 18432

typedef unsigned int u32;
typedef unsigned short u16;
typedef _Float16 hf;

__device__ __forceinline__ float bf_lo(u32 u) {
    union { u32 i; float f; } c; c.i = u << 16; return c.f;
}
__device__ __forceinline__ float bf_hi(u32 u) {
    union { u32 i; float f; } c; c.i = u & 0xffff0000u; return c.f;
}
__device__ __forceinline__ u32 f2bf_rne(float f) {
    union { float f; u32 u; } c; c.f = f;
    u32 u = c.u;
    u += 0x7fffu + ((u >> 16) & 1u);   // round-to-nearest-even
    return u >> 16;
}
__device__ __forceinline__ u32 f2h(float f) {
    union { u16 s; hf h; } c; c.h = (hf)f; return (u32)c.s;
}
__device__ __forceinline__ float h_lo(u32 u) {
    union { u16 s; hf h; } c; c.s = (u16)(u & 0xffffu); return (float)c.h;
}
__device__ __forceinline__ float h_hi(u32 u) {
    union { u16 s; hf h; } c; c.s = (u16)(u >> 16); return (float)c.h;
}

// ---------------------------------------------------------------------------
// Kernel 1: merged prep.  blockIdx%6==5 -> bin branch, else node_pre branch.
// Both branches overlap on the machine (independent inputs/outputs).
// ---------------------------------------------------------------------------
__global__ __launch_bounds__(256) void prep_k(
    const float* __restrict__ x, const float* __restrict__ W1,
    const float* __restrict__ b1, u16* __restrict__ Ah,
    u16* __restrict__ Bmh, const int* __restrict__ ei,
    u32* __restrict__ slotB, int* __restrict__ gcnt,
    int N, int E, int NB, int nPre, int nBin)
{
    __shared__ __align__(16) char smem[PRE_SMEM];
    const int idx = blockIdx.x;
    const int tid = threadIdx.x;

    if ((idx % 6) == 5) {
        // ---------------- bin branch (R6 bin_k body) ----------------
        const int bb = idx / 6;
        if (bb >= nBin) return;
        int* histL = (int*)smem;
        int* gbase = histL + MAXB;
        const int e0 = bb * EPB;

        for (int j = tid; j < NB; j += 256) histL[j] = 0;
        __syncthreads();

        #pragma unroll
        for (int i = 0; i < EPB / 256; ++i) {
            int e = e0 + i * 256 + tid;
            if (e < E) {
                int d = ei[E + e];
                atomicAdd(&histL[d >> BSH], 1);
            }
        }
        __syncthreads();

        for (int j = tid; j < NB; j += 256) {
            int h = histL[j];
            gbase[j] = (h > 0) ? atomicAdd(&gcnt[j], h) : 0;
            histL[j] = 0;                 // reuse as local append pos
        }
        __syncthreads();

        #pragma unroll
        for (int i = 0; i < EPB / 256; ++i) {
            int e = e0 + i * 256 + tid;
            if (e < E) {
                int s = ei[e];
                int d = ei[E + e];
                int b = d >> BSH;
                int pos = gbase[b] + atomicAdd(&histL[b], 1);
                if (pos < CAPB)
                    slotB[(size_t)b * CAPB + pos] =
                        ((u32)(d & (BN - 1)) << 20) | (u32)s;
            }
        }
        return;
    }

    // ---------------- node_pre branch ----------------
    const int pb = idx - idx / 6;
    if (pb >= nPre) return;
    float (*Wc)[132] = (float(*)[132])smem;              // 33792 B
    float (*xsT)[72] = (float(*)[72])(smem + 33792);     // 18432 B

    const int node0 = pb * 64;

    for (int i = tid; i < 64 * 128; i += 256) {
        int k = i >> 7, c = i & 127;
        int cc = c & 63;
        float wb = W1[(64 + k) * 64 + cc];
        Wc[k][c] = (c < 64) ? (W1[k * 64 + cc] - wb) : wb;
    }
    // Transpose-stage x: lane n = tid&63 owns node n's column writes.
    // LDS write addr = kk*72 + n -> bank n%32: 2-way, conflict-free.
    // Global reads column-strided but the 16 KB tile stays L1-resident.
    {
        const int n = tid & 63;
        const int gn = node0 + n;
        const bool ok = gn < N;
        const int kb = tid >> 6;
        #pragma unroll
        for (int j = 0; j < 16; ++j) {
            int kk = kb + 4 * j;
            xsT[kk][n] = ok ? x[(size_t)gn * 64 + kk] : 0.f;
        }
    }
    __syncthreads();

    const int ng = tid & 15, cg = tid >> 4;
    const int n0 = ng * 4, c0 = cg * 8;

    float acc[4][8];
    #pragma unroll
    for (int ci = 0; ci < 8; ++ci) {
        float init = (c0 + ci < 64) ? b1[c0 + ci] : 0.f;
        #pragma unroll
        for (int ni = 0; ni < 4; ++ni) acc[ni][ci] = init;
    }

    #pragma unroll 4
    for (int k = 0; k < 64; ++k) {
        float4 xv = *(const float4*)&xsT[k][n0];
        float4 wa = *(const float4*)&Wc[k][c0];
        float4 wb = *(const float4*)&Wc[k][c0 + 4];
        float xs[4] = {xv.x, xv.y, xv.z, xv.w};
        float ws[8] = {wa.x, wa.y, wa.z, wa.w, wb.x, wb.y, wb.z, wb.w};
        #pragma unroll
        for (int ni = 0; ni < 4; ++ni)
            #pragma unroll
            for (int ci = 0; ci < 8; ++ci)
                acc[ni][ci] += xs[ni] * ws[ci];
    }

    #pragma unroll
    for (int ni = 0; ni < 4; ++ni) {
        int n = node0 + n0 + ni;
        if (n >= N) break;
        if (c0 < 64) {
            uint4 pk;
            pk.x = f2h(acc[ni][0]) | (f2h(acc[ni][1]) << 16);
            pk.y = f2h(acc[ni][2]) | (f2h(acc[ni][3]) << 16);
            pk.z = f2h(acc[ni][4]) | (f2h(acc[ni][5]) << 16);
            pk.w = f2h(acc[ni][6]) | (f2h(acc[ni][7]) << 16);
            *(uint4*)&Ah[(size_t)n * 64 + c0] = pk;
        } else {
            uint4 pk;
            pk.x = f2bf_rne(acc[ni][0]) | (f2bf_rne(acc[ni][1]) << 16);
            pk.y = f2bf_rne(acc[ni][2]) | (f2bf_rne(acc[ni][3]) << 16);
            pk.z = f2bf_rne(acc[ni][4]) | (f2bf_rne(acc[ni][5]) << 16);
            pk.w = f2bf_rne(acc[ni][6]) | (f2bf_rne(acc[ni][7]) << 16);
            *(uint4*)&Bmh[(size_t)n * 64 + (c0 - 64)] = pk;
        }
    }
}

// ---------------------------------------------------------------------------
// Kernel 2: per-bucket CSR build + aggregate + W2 GEMM + tanh.
// (R6 structure; A loads f16.)
// ---------------------------------------------------------------------------
__device__ __forceinline__ float4 relu4add(float4 acc, float4 a, float4 b) {
    acc.x += fmaxf(a.x + b.x, 0.f);
    acc.y += fmaxf(a.y + b.y, 0.f);
    acc.z += fmaxf(a.z + b.z, 0.f);
    acc.w += fmaxf(a.w + b.w, 0.f);
    return acc;
}
__device__ __forceinline__ float4 relu4add_m(float4 acc, float4 a, float4 b, bool m) {
    acc.x += m ? fmaxf(a.x + b.x, 0.f) : 0.f;
    acc.y += m ? fmaxf(a.y + b.y, 0.f) : 0.f;
    acc.z += m ? fmaxf(a.z + b.z, 0.f) : 0.f;
    acc.w += m ? fmaxf(a.w + b.w, 0.f) : 0.f;
    return acc;
}
__device__ __forceinline__ float4 bf4(uint2 u) {
    return make_float4(bf_lo(u.x), bf_hi(u.x), bf_lo(u.y), bf_hi(u.y));
}

__global__ __launch_bounds__(256) void fused_agg(
    const u16* __restrict__ Ah, const u16* __restrict__ Bmh,
    const u32* __restrict__ slotB, const int* __restrict__ gcnt,
    const float* __restrict__ W2, const float* __restrict__ b2,
    float* __restrict__ out, int N)
{
    __shared__ __align__(16) float W2s[64][68];      // 17.4 KB
    __shared__ __align__(16) u32 pool[BN * 17 * 2];  // 17.4 KB: eStage then aggTb
    __shared__ u32 csrS[CAPB];                       // 8 KB
    __shared__ int histL[BN];
    __shared__ int rowO[BN + 1];
    __shared__ int ofs[BN];
    __shared__ float b2s[64];

    u32* eStage = pool;                              // [CAPB] (phase: CSR build)
    uint2* aggTb = (uint2*)pool;                     // [BN][17] (phase: agg)

    const int tid = threadIdx.x;
    const int b = blockIdx.x;
    const int node0 = b * BN;
    const int cntB = min(gcnt[b], CAPB);

    for (int i = tid; i < 1024; i += 256)
        *(float4*)&W2s[i >> 4][(i & 15) * 4] = ((const float4*)W2)[i];
    if (tid < 64) b2s[tid] = b2[tid];
    if (tid < BN) histL[tid] = 0;
    __syncthreads();

    for (int i = tid; i < cntB; i += 256) {
        u32 e = slotB[(size_t)b * CAPB + i];
        eStage[i] = e;
        atomicAdd(&histL[e >> 20], 1);
    }
    __syncthreads();

    if (tid < 64) {                                  // exclusive scan of 128 bins
        int l = tid;
        int h0 = histL[2 * l], h1 = histL[2 * l + 1];
        int s = h0 + h1, inc = s;
        #pragma unroll
        for (int off = 1; off < 64; off <<= 1) {
            int t = __shfl_up(inc, off);
            if (l >= off) inc += t;
        }
        int base = inc - s;
        rowO[2 * l] = base; rowO[2 * l + 1] = base + h0;
        ofs[2 * l] = base;  ofs[2 * l + 1] = base + h0;
        if (l == 63) rowO[BN] = inc;
    }
    __syncthreads();

    for (int i = tid; i < cntB; i += 256) {
        u32 e = eStage[i];
        int pos = atomicAdd(&ofs[e >> 20], 1);
        csrS[pos] = e & 0xFFFFFu;
    }
    __syncthreads();                                 // eStage dead; aggTb live

    // ---- Phase 1: gather-aggregate (aggT packed f16) ----
    {
        const int q = tid & 15, ng = tid >> 4;
        const uint2* __restrict__ B2 = (const uint2*)Bmh;
        const uint2* __restrict__ A2 = (const uint2*)Ah;
        #pragma unroll
        for (int h = 0; h < 8; ++h) {
            int nl = ng + h * 16;
            int gn = node0 + nl;
            int start = rowO[nl];
            int d = (gn < N) ? (rowO[nl + 1] - start) : 0;
            float4 a = make_float4(0.f, 0.f, 0.f, 0.f);
            if (gn < N) {
                uint2 ua = A2[(size_t)gn * 16 + q];
                a = make_float4(h_lo(ua.x), h_hi(ua.x), h_lo(ua.y), h_hi(ua.y));
            }
            float4 acc = make_float4(0.f, 0.f, 0.f, 0.f);

            const int dfull = d & ~3;
            int j = 0;
            for (; j < dfull; j += 4) {
                int s0 = csrS[start + j + 0];
                int s1 = csrS[start + j + 1];
                int s2 = csrS[start + j + 2];
                int s3 = csrS[start + j + 3];
                uint2 b0 = B2[(size_t)s0 * 16 + q];
                uint2 b1v = B2[(size_t)s1 * 16 + q];
                uint2 b2v = B2[(size_t)s2 * 16 + q];
                uint2 b3v = B2[(size_t)s3 * 16 + q];
                acc = relu4add(acc, a, bf4(b0));
                acc = relu4add(acc, a, bf4(b1v));
                acc = relu4add(acc, a, bf4(b2v));
                acc = relu4add(acc, a, bf4(b3v));
            }
            if (j < d) {
                int s0 = csrS[start + j];
                int s1 = csrS[start + min(j + 1, d - 1)];
                int s2 = csrS[start + min(j + 2, d - 1)];
                uint2 b0 = B2[(size_t)s0 * 16 + q];
                uint2 b1v = B2[(size_t)s1 * 16 + q];
                uint2 b2v = B2[(size_t)s2 * 16 + q];
                acc = relu4add(acc, a, bf4(b0));
                acc = relu4add_m(acc, a, bf4(b1v), j + 1 < d);
                acc = relu4add_m(acc, a, bf4(b2v), j + 2 < d);
            }
            uint2 pk;
            pk.x = f2h(acc.x) | (f2h(acc.y) << 16);
            pk.y = f2h(acc.z) | (f2h(acc.w) << 16);
            aggTb[nl * 17 + q] = pk;
        }
    }
    __syncthreads();

    // ---- Phase 2: [128x64] @ W2 + deg*b2, tanh; W2 shared across 4 nodes ----
    {
        const int cg = tid & 15, g0 = tid >> 4;
        const int c0 = cg * 4;
        #pragma unroll
        for (int h = 0; h < 2; ++h) {
            int g = g0 + h * 16;       // 0..31
            int nb0 = g * 4;           // nodes nb0..nb0+3 (adjacent: bank-safe)
            float o[4][4];
            #pragma unroll
            for (int ni = 0; ni < 4; ++ni) {
                float dg = (float)(rowO[nb0 + ni + 1] - rowO[nb0 + ni]);
                #pragma unroll
                for (int ci = 0; ci < 4; ++ci) o[ni][ci] = dg * b2s[c0 + ci];
            }
            #pragma unroll 2
            for (int kc = 0; kc < 16; ++kc) {
                uint2 u0 = aggTb[(nb0 + 0) * 17 + kc];
                uint2 u1 = aggTb[(nb0 + 1) * 17 + kc];
                uint2 u2 = aggTb[(nb0 + 2) * 17 + kc];
                uint2 u3 = aggTb[(nb0 + 3) * 17 + kc];
                #pragma unroll
                for (int kk = 0; kk < 4; ++kk) {
                    float4 wv = *(const float4*)&W2s[kc * 4 + kk][c0];
                    float a0 = (kk < 2) ? ((kk == 0) ? h_lo(u0.x) : h_hi(u0.x))
                                        : ((kk == 2) ? h_lo(u0.y) : h_hi(u0.y));
                    float a1 = (kk < 2) ? ((kk == 0) ? h_lo(u1.x) : h_hi(u1.x))
                                        : ((kk == 2) ? h_lo(u1.y) : h_hi(u1.y));
                    float a2 = (kk < 2) ? ((kk == 0) ? h_lo(u2.x) : h_hi(u2.x))
                                        : ((kk == 2) ? h_lo(u2.y) : h_hi(u2.y));
                    float a3 = (kk < 2) ? ((kk == 0) ? h_lo(u3.x) : h_hi(u3.x))
                                        : ((kk == 2) ? h_lo(u3.y) : h_hi(u3.y));
                    o[0][0] += a0 * wv.x; o[0][1] += a0 * wv.y; o[0][2] += a0 * wv.z; o[0][3] += a0 * wv.w;
                    o[1][0] += a1 * wv.x; o[1][1] += a1 * wv.y; o[1][2] += a1 * wv.z; o[1][3] += a1 * wv.w;
                    o[2][0] += a2 * wv.x; o[2][1] += a2 * wv.y; o[2][2] += a2 * wv.z; o[2][3] += a2 * wv.w;
                    o[3][0] += a3 * wv.x; o[3][1] += a3 * wv.y; o[3][2] += a3 * wv.z; o[3][3] += a3 * wv.w;
                }
            }
            #pragma unroll
            for (int ni = 0; ni < 4; ++ni) {
                int gn = node0 + nb0 + ni;
                if (gn < N) {
                    float4 r = make_float4(tanhf(o[ni][0]), tanhf(o[ni][1]),
                                           tanhf(o[ni][2]), tanhf(o[ni][3]));
                    ((float4*)out)[(size_t)gn * 16 + cg] = r;
                }
            }
        }
    }
}

// ---------------------------------------------------------------------------
extern "C" void kernel_launch(void* const* d_in, const int* in_sizes, int n_in,
                              void* d_out, int out_size, void* d_ws, size_t ws_size,
                              hipStream_t stream)
{
    const float* x  = (const float*)d_in[0];
    const int*   ei = (const int*)d_in[1];     // [2,E]: row0=src, row1=dst
    const float* W1 = (const float*)d_in[2];   // [128,64]
    const float* b1 = (const float*)d_in[3];   // [64]
    const float* W2 = (const float*)d_in[4];   // [64,64]
    const float* b2 = (const float*)d_in[5];   // [64]
    float* out = (float*)d_out;

    const int N = in_sizes[0] / FDIM;          // 100000
    const int E = in_sizes[1] / 2;             // 1200000
    const int NB = (N + BN - 1) / BN;          // 782 buckets

    // Workspace (re-poisoned 0xAA every call; gcnt zeroed below):
    u16*   Ah    = (u16*)d_ws;                          // N*64 f16  = 12.8 MB
    u16*   Bmh   = Ah + (size_t)N * FDIM;               // N*64 bf16 = 12.8 MB
    u32*   slotB = (u32*)(Bmh + (size_t)N * FDIM);      // NB*CAPB u32 = 6.4 MB
    int*   gcnt  = (int*)(slotB + (size_t)NB * CAPB);   // NB i32

    hipMemsetAsync(gcnt, 0, (size_t)NB * sizeof(int), stream);

    // Interleaved heterogeneous grid: 1 bin block per 6 (idx%6==5), rest pre.
    const int nPre = (N + 63) / 64;            // 1563
    const int nBin = (E + EPB - 1) / EPB;      // 293
    int T = (nPre * 6 + 4) / 5;
    while (T - T / 6 < nPre) ++T;
    if (T < 6 * nBin) T = 6 * nBin;

    prep_k<<<T, 256, 0, stream>>>(x, W1, b1, Ah, Bmh, ei, slotB, gcnt,
                                  N, E, NB, nPre, nBin);
    fused_agg<<<NB, 256, 0, stream>>>(Ah, Bmh, slotB, gcnt, W2, b2, out, N);
}

// Round 8
// 198.673 us; speedup vs baseline: 6.7733x; 1.0781x over previous
//
#include <hip/hip_runtime.h>
#include <math.h>

// EdgeConv, factorized:
//   A[i] = x[i] @ (W1_top - W1_bot) + b1        (64-dim f16, per node)
//   B[j] = x[j] @ W1_bot                        (64-dim bf16, per node)
//   agg1[i] = sum_{e: dst=i} relu(A[i] + B[src_e])
//   out[i]  = tanh(agg1[i] @ W2 + deg_i * b2)
//
// R7 -> R8 (fused_agg only): W2 LDS tile in f16 (45 KB -> 36 KB LDS =>
// 4 blocks/CU instead of 3) and phase-1 edge batch widened 4 -> 8
// independent gathers per round (halves the latency-round count).
// prep_k (merged node_pre + bin, 5:1 interleave) unchanged from R7.

#define FDIM 64
#define BN 128            // nodes per bucket
#define BSH 7             // log2(BN)
#define CAPB 2048         // bucket capacity (mean 1536, +13 sigma)
#define MAXB 1024         // LDS bucket-counter array bound in bin branch
#define EPB 4096          // edges per bin block
#define PRE_SMEM 52224    // bytes: Wc 33792 + xsT 18432

typedef unsigned int u32;
typedef unsigned short u16;
typedef _Float16 hf;

__device__ __forceinline__ float bf_lo(u32 u) {
    union { u32 i; float f; } c; c.i = u << 16; return c.f;
}
__device__ __forceinline__ float bf_hi(u32 u) {
    union { u32 i; float f; } c; c.i = u & 0xffff0000u; return c.f;
}
__device__ __forceinline__ u32 f2bf_rne(float f) {
    union { float f; u32 u; } c; c.f = f;
    u32 u = c.u;
    u += 0x7fffu + ((u >> 16) & 1u);   // round-to-nearest-even
    return u >> 16;
}
__device__ __forceinline__ u32 f2h(float f) {
    union { u16 s; hf h; } c; c.h = (hf)f; return (u32)c.s;
}
__device__ __forceinline__ float h_lo(u32 u) {
    union { u16 s; hf h; } c; c.s = (u16)(u & 0xffffu); return (float)c.h;
}
__device__ __forceinline__ float h_hi(u32 u) {
    union { u16 s; hf h; } c; c.s = (u16)(u >> 16); return (float)c.h;
}

// ---------------------------------------------------------------------------
// Kernel 1: merged prep.  blockIdx%6==5 -> bin branch, else node_pre branch.
// (unchanged from R7)
// ---------------------------------------------------------------------------
__global__ __launch_bounds__(256) void prep_k(
    const float* __restrict__ x, const float* __restrict__ W1,
    const float* __restrict__ b1, u16* __restrict__ Ah,
    u16* __restrict__ Bmh, const int* __restrict__ ei,
    u32* __restrict__ slotB, int* __restrict__ gcnt,
    int N, int E, int NB, int nPre, int nBin)
{
    __shared__ __align__(16) char smem[PRE_SMEM];
    const int idx = blockIdx.x;
    const int tid = threadIdx.x;

    if ((idx % 6) == 5) {
        // ---------------- bin branch ----------------
        const int bb = idx / 6;
        if (bb >= nBin) return;
        int* histL = (int*)smem;
        int* gbase = histL + MAXB;
        const int e0 = bb * EPB;

        for (int j = tid; j < NB; j += 256) histL[j] = 0;
        __syncthreads();

        #pragma unroll
        for (int i = 0; i < EPB / 256; ++i) {
            int e = e0 + i * 256 + tid;
            if (e < E) {
                int d = ei[E + e];
                atomicAdd(&histL[d >> BSH], 1);
            }
        }
        __syncthreads();

        for (int j = tid; j < NB; j += 256) {
            int h = histL[j];
            gbase[j] = (h > 0) ? atomicAdd(&gcnt[j], h) : 0;
            histL[j] = 0;                 // reuse as local append pos
        }
        __syncthreads();

        #pragma unroll
        for (int i = 0; i < EPB / 256; ++i) {
            int e = e0 + i * 256 + tid;
            if (e < E) {
                int s = ei[e];
                int d = ei[E + e];
                int b = d >> BSH;
                int pos = gbase[b] + atomicAdd(&histL[b], 1);
                if (pos < CAPB)
                    slotB[(size_t)b * CAPB + pos] =
                        ((u32)(d & (BN - 1)) << 20) | (u32)s;
            }
        }
        return;
    }

    // ---------------- node_pre branch ----------------
    const int pb = idx - idx / 6;
    if (pb >= nPre) return;
    float (*Wc)[132] = (float(*)[132])smem;              // 33792 B
    float (*xsT)[72] = (float(*)[72])(smem + 33792);     // 18432 B

    const int node0 = pb * 64;

    for (int i = tid; i < 64 * 128; i += 256) {
        int k = i >> 7, c = i & 127;
        int cc = c & 63;
        float wb = W1[(64 + k) * 64 + cc];
        Wc[k][c] = (c < 64) ? (W1[k * 64 + cc] - wb) : wb;
    }
    {
        const int n = tid & 63;
        const int gn = node0 + n;
        const bool ok = gn < N;
        const int kb = tid >> 6;
        #pragma unroll
        for (int j = 0; j < 16; ++j) {
            int kk = kb + 4 * j;
            xsT[kk][n] = ok ? x[(size_t)gn * 64 + kk] : 0.f;
        }
    }
    __syncthreads();

    const int ng = tid & 15, cg = tid >> 4;
    const int n0 = ng * 4, c0 = cg * 8;

    float acc[4][8];
    #pragma unroll
    for (int ci = 0; ci < 8; ++ci) {
        float init = (c0 + ci < 64) ? b1[c0 + ci] : 0.f;
        #pragma unroll
        for (int ni = 0; ni < 4; ++ni) acc[ni][ci] = init;
    }

    #pragma unroll 4
    for (int k = 0; k < 64; ++k) {
        float4 xv = *(const float4*)&xsT[k][n0];
        float4 wa = *(const float4*)&Wc[k][c0];
        float4 wb = *(const float4*)&Wc[k][c0 + 4];
        float xs[4] = {xv.x, xv.y, xv.z, xv.w};
        float ws[8] = {wa.x, wa.y, wa.z, wa.w, wb.x, wb.y, wb.z, wb.w};
        #pragma unroll
        for (int ni = 0; ni < 4; ++ni)
            #pragma unroll
            for (int ci = 0; ci < 8; ++ci)
                acc[ni][ci] += xs[ni] * ws[ci];
    }

    #pragma unroll
    for (int ni = 0; ni < 4; ++ni) {
        int n = node0 + n0 + ni;
        if (n >= N) break;
        if (c0 < 64) {
            uint4 pk;
            pk.x = f2h(acc[ni][0]) | (f2h(acc[ni][1]) << 16);
            pk.y = f2h(acc[ni][2]) | (f2h(acc[ni][3]) << 16);
            pk.z = f2h(acc[ni][4]) | (f2h(acc[ni][5]) << 16);
            pk.w = f2h(acc[ni][6]) | (f2h(acc[ni][7]) << 16);
            *(uint4*)&Ah[(size_t)n * 64 + c0] = pk;
        } else {
            uint4 pk;
            pk.x = f2bf_rne(acc[ni][0]) | (f2bf_rne(acc[ni][1]) << 16);
            pk.y = f2bf_rne(acc[ni][2]) | (f2bf_rne(acc[ni][3]) << 16);
            pk.z = f2bf_rne(acc[ni][4]) | (f2bf_rne(acc[ni][5]) << 16);
            pk.w = f2bf_rne(acc[ni][6]) | (f2bf_rne(acc[ni][7]) << 16);
            *(uint4*)&Bmh[(size_t)n * 64 + (c0 - 64)] = pk;
        }
    }
}

// ---------------------------------------------------------------------------
// Kernel 2: per-bucket CSR build + aggregate + W2 GEMM + tanh.
// LDS ~36 KB -> 4 blocks/CU; phase-1 batches 8 independent gathers.
// ---------------------------------------------------------------------------
__device__ __forceinline__ float4 relu4add(float4 acc, float4 a, float4 b) {
    acc.x += fmaxf(a.x + b.x, 0.f);
    acc.y += fmaxf(a.y + b.y, 0.f);
    acc.z += fmaxf(a.z + b.z, 0.f);
    acc.w += fmaxf(a.w + b.w, 0.f);
    return acc;
}
__device__ __forceinline__ float4 relu4add_m(float4 acc, float4 a, float4 b, bool m) {
    acc.x += m ? fmaxf(a.x + b.x, 0.f) : 0.f;
    acc.y += m ? fmaxf(a.y + b.y, 0.f) : 0.f;
    acc.z += m ? fmaxf(a.z + b.z, 0.f) : 0.f;
    acc.w += m ? fmaxf(a.w + b.w, 0.f) : 0.f;
    return acc;
}
__device__ __forceinline__ float4 bf4(uint2 u) {
    return make_float4(bf_lo(u.x), bf_hi(u.x), bf_lo(u.y), bf_hi(u.y));
}

__global__ __launch_bounds__(256) void fused_agg(
    const u16* __restrict__ Ah, const u16* __restrict__ Bmh,
    const u32* __restrict__ slotB, const int* __restrict__ gcnt,
    const float* __restrict__ W2, const float* __restrict__ b2,
    float* __restrict__ out, int N)
{
    __shared__ __align__(16) u32 W2h[64][34];        // f16-packed W2, 8.7 KB
    __shared__ __align__(16) u32 pool[BN * 17 * 2];  // 17.4 KB: eStage then aggTb
    __shared__ u32 csrS[CAPB];                       // 8 KB
    __shared__ int histL[BN];
    __shared__ int rowO[BN + 1];
    __shared__ int ofs[BN];
    __shared__ float b2s[64];

    u32* eStage = pool;                              // [CAPB] (phase: CSR build)
    uint2* aggTb = (uint2*)pool;                     // [BN][17] (phase: agg)

    const int tid = threadIdx.x;
    const int b = blockIdx.x;
    const int node0 = b * BN;
    const int cntB = min(gcnt[b], CAPB);

    // Stage W2 -> f16 pairs: W2h[k][c/2] = (f16(W2[k][c]), f16(W2[k][c+1]))
    for (int i = tid; i < 1024; i += 256) {
        int k = i >> 4, c4 = (i & 15) * 4;
        float4 w = *(const float4*)&W2[k * 64 + c4];
        uint2 pk;
        pk.x = f2h(w.x) | (f2h(w.y) << 16);
        pk.y = f2h(w.z) | (f2h(w.w) << 16);
        *(uint2*)&W2h[k][c4 >> 1] = pk;
    }
    if (tid < 64) b2s[tid] = b2[tid];
    if (tid < BN) histL[tid] = 0;
    __syncthreads();

    for (int i = tid; i < cntB; i += 256) {
        u32 e = slotB[(size_t)b * CAPB + i];
        eStage[i] = e;
        atomicAdd(&histL[e >> 20], 1);
    }
    __syncthreads();

    if (tid < 64) {                                  // exclusive scan of 128 bins
        int l = tid;
        int h0 = histL[2 * l], h1 = histL[2 * l + 1];
        int s = h0 + h1, inc = s;
        #pragma unroll
        for (int off = 1; off < 64; off <<= 1) {
            int t = __shfl_up(inc, off);
            if (l >= off) inc += t;
        }
        int base = inc - s;
        rowO[2 * l] = base; rowO[2 * l + 1] = base + h0;
        ofs[2 * l] = base;  ofs[2 * l + 1] = base + h0;
        if (l == 63) rowO[BN] = inc;
    }
    __syncthreads();

    for (int i = tid; i < cntB; i += 256) {
        u32 e = eStage[i];
        int pos = atomicAdd(&ofs[e >> 20], 1);
        csrS[pos] = e & 0xFFFFFu;
    }
    __syncthreads();                                 // eStage dead; aggTb live

    // ---- Phase 1: gather-aggregate, 8 independent gathers per round ----
    {
        const int q = tid & 15, ng = tid >> 4;
        const uint2* __restrict__ B2 = (const uint2*)Bmh;
        const uint2* __restrict__ A2 = (const uint2*)Ah;
        #pragma unroll
        for (int h = 0; h < 8; ++h) {
            int nl = ng + h * 16;
            int gn = node0 + nl;
            int start = rowO[nl];
            int d = (gn < N) ? (rowO[nl + 1] - start) : 0;
            float4 a = make_float4(0.f, 0.f, 0.f, 0.f);
            if (gn < N) {
                uint2 ua = A2[(size_t)gn * 16 + q];
                a = make_float4(h_lo(ua.x), h_hi(ua.x), h_lo(ua.y), h_hi(ua.y));
            }
            float4 acc = make_float4(0.f, 0.f, 0.f, 0.f);

            int j = 0;
            for (; j + 8 <= d; j += 8) {             // exact 8-batches
                int ss[8];
                uint2 bb[8];
                #pragma unroll
                for (int t = 0; t < 8; ++t) ss[t] = csrS[start + j + t];
                #pragma unroll
                for (int t = 0; t < 8; ++t) bb[t] = B2[(size_t)ss[t] * 16 + q];
                #pragma unroll
                for (int t = 0; t < 8; ++t) acc = relu4add(acc, a, bf4(bb[t]));
            }
            if (j < d) {                             // masked 8-tail (clamped idx)
                int ss[8];
                uint2 bb[8];
                #pragma unroll
                for (int t = 0; t < 8; ++t) ss[t] = csrS[start + min(j + t, d - 1)];
                #pragma unroll
                for (int t = 0; t < 8; ++t) bb[t] = B2[(size_t)ss[t] * 16 + q];
                acc = relu4add(acc, a, bf4(bb[0]));
                #pragma unroll
                for (int t = 1; t < 8; ++t)
                    acc = relu4add_m(acc, a, bf4(bb[t]), j + t < d);
            }
            uint2 pk;
            pk.x = f2h(acc.x) | (f2h(acc.y) << 16);
            pk.y = f2h(acc.z) | (f2h(acc.w) << 16);
            aggTb[nl * 17 + q] = pk;
        }
    }
    __syncthreads();

    // ---- Phase 2: [128x64] @ W2 + deg*b2, tanh; W2 f16 from LDS ----
    {
        const int cg = tid & 15, g0 = tid >> 4;
        const int c0 = cg * 4;
        #pragma unroll
        for (int h = 0; h < 2; ++h) {
            int g = g0 + h * 16;       // 0..31
            int nb0 = g * 4;           // nodes nb0..nb0+3
            float o[4][4];
            #pragma unroll
            for (int ni = 0; ni < 4; ++ni) {
                float dg = (float)(rowO[nb0 + ni + 1] - rowO[nb0 + ni]);
                #pragma unroll
                for (int ci = 0; ci < 4; ++ci) o[ni][ci] = dg * b2s[c0 + ci];
            }
            #pragma unroll 2
            for (int kc = 0; kc < 16; ++kc) {
                uint2 u0 = aggTb[(nb0 + 0) * 17 + kc];
                uint2 u1 = aggTb[(nb0 + 1) * 17 + kc];
                uint2 u2 = aggTb[(nb0 + 2) * 17 + kc];
                uint2 u3 = aggTb[(nb0 + 3) * 17 + kc];
                #pragma unroll
                for (int kk = 0; kk < 4; ++kk) {
                    uint2 w2p = *(const uint2*)&W2h[kc * 4 + kk][cg * 2];
                    float wv[4] = {h_lo(w2p.x), h_hi(w2p.x), h_lo(w2p.y), h_hi(w2p.y)};
                    float a0 = (kk < 2) ? ((kk == 0) ? h_lo(u0.x) : h_hi(u0.x))
                                        : ((kk == 2) ? h_lo(u0.y) : h_hi(u0.y));
                    float a1 = (kk < 2) ? ((kk == 0) ? h_lo(u1.x) : h_hi(u1.x))
                                        : ((kk == 2) ? h_lo(u1.y) : h_hi(u1.y));
                    float a2 = (kk < 2) ? ((kk == 0) ? h_lo(u2.x) : h_hi(u2.x))
                                        : ((kk == 2) ? h_lo(u2.y) : h_hi(u2.y));
                    float a3 = (kk < 2) ? ((kk == 0) ? h_lo(u3.x) : h_hi(u3.x))
                                        : ((kk == 2) ? h_lo(u3.y) : h_hi(u3.y));
                    #pragma unroll
                    for (int ci = 0; ci < 4; ++ci) {
                        o[0][ci] += a0 * wv[ci];
                        o[1][ci] += a1 * wv[ci];
                        o[2][ci] += a2 * wv[ci];
                        o[3][ci] += a3 * wv[ci];
                    }
                }
            }
            #pragma unroll
            for (int ni = 0; ni < 4; ++ni) {
                int gn = node0 + nb0 + ni;
                if (gn < N) {
                    float4 r = make_float4(tanhf(o[ni][0]), tanhf(o[ni][1]),
                                           tanhf(o[ni][2]), tanhf(o[ni][3]));
                    ((float4*)out)[(size_t)gn * 16 + cg] = r;
                }
            }
        }
    }
}

// ---------------------------------------------------------------------------
extern "C" void kernel_launch(void* const* d_in, const int* in_sizes, int n_in,
                              void* d_out, int out_size, void* d_ws, size_t ws_size,
                              hipStream_t stream)
{
    const float* x  = (const float*)d_in[0];
    const int*   ei = (const int*)d_in[1];     // [2,E]: row0=src, row1=dst
    const float* W1 = (const float*)d_in[2];   // [128,64]
    const float* b1 = (const float*)d_in[3];   // [64]
    const float* W2 = (const float*)d_in[4];   // [64,64]
    const float* b2 = (const float*)d_in[5];   // [64]
    float* out = (float*)d_out;

    const int N = in_sizes[0] / FDIM;          // 100000
    const int E = in_sizes[1] / 2;             // 1200000
    const int NB = (N + BN - 1) / BN;          // 782 buckets

    // Workspace (re-poisoned 0xAA every call; gcnt zeroed below):
    u16*   Ah    = (u16*)d_ws;                          // N*64 f16  = 12.8 MB
    u16*   Bmh   = Ah + (size_t)N * FDIM;               // N*64 bf16 = 12.8 MB
    u32*   slotB = (u32*)(Bmh + (size_t)N * FDIM);      // NB*CAPB u32 = 6.4 MB
    int*   gcnt  = (int*)(slotB + (size_t)NB * CAPB);   // NB i32

    hipMemsetAsync(gcnt, 0, (size_t)NB * sizeof(int), stream);

    // Interleaved heterogeneous grid: 1 bin block per 6 (idx%6==5), rest pre.
    const int nPre = (N + 63) / 64;            // 1563
    const int nBin = (E + EPB - 1) / EPB;      // 293
    int T = (nPre * 6 + 4) / 5;
    while (T - T / 6 < nPre) ++T;
    if (T < 6 * nBin) T = 6 * nBin;

    prep_k<<<T, 256, 0, stream>>>(x, W1, b1, Ah, Bmh, ei, slotB, gcnt,
                                  N, E, NB, nPre, nBin);
    fused_agg<<<NB, 256, 0, stream>>>(Ah, Bmh, slotB, gcnt, W2, b2, out, N);
}